// Round 8
// baseline (1624.234 us; speedup 1.0000x reference)
//
#include <hip/hip_runtime.h>
#include <cstdint>

typedef unsigned long long u64;
typedef unsigned int u32;
typedef float v2f __attribute__((ext_vector_type(2)));

#define NB 8
#define NP 4096
#define NK 64
#define NM 1024
#define NF 64
#define NOUT 128
#define R2C 0.04f      // float(0.2*0.2 in double) == 0x3D23D70A
#define CAP 2048
#define FPS_T 512      // 8 waves: 4 per cloud, 2 clouds per block
#define FPS_W 4        // waves per cloud
#define FPS_Q 16       // points per lane (8 float2)

// Exact (non-contracted) squared distance, left-to-right sum, matching XLA's
// elementwise (a-b)**2 then reduce over the size-3 axis.
static __device__ __forceinline__ float sq3(float ax, float ay, float az,
                                            float bx, float by, float bz) {
  float dx = __fsub_rn(ax, bx), dy = __fsub_rn(ay, by), dz = __fsub_rn(az, bz);
  return __fadd_rn(__fadd_rn(__fmul_rn(dx, dx), __fmul_rn(dy, dy)), __fmul_rn(dz, dz));
}

// f32 max with a DPP-shifted copy; bound_ctrl=1 feeds 0.0f (safe: d2 >= 0)
template <int CTRL>
static __device__ __forceinline__ float dpp_maxf(float x) {
  int m = __builtin_amdgcn_update_dpp(0, __float_as_int(x), CTRL, 0xf, 0xf, true);
  return fmaxf(x, __int_as_float(m));
}

static __device__ __forceinline__ u64 umax64(u64 a, u64 b) { return a > b ? a : b; }

// ---- kernel 0: transpose weights into ws (ch-major rows -> uniform s_load) ----
__global__ void prep_weights(const float* __restrict__ W1, const float* __restrict__ W2,
                             const float* __restrict__ W3,
                             float* __restrict__ w1t, float* __restrict__ w2t,
                             float* __restrict__ w3t) {
  int t = blockIdx.x * blockDim.x + threadIdx.x;
  int stride = gridDim.x * blockDim.x;
  for (int idx = t; idx < 64 * 67; idx += stride) {
    int ch = idx / 67, i = idx - ch * 67;
    w1t[idx] = W1[i * 64 + ch];
  }
  for (int idx = t; idx < 64 * 64; idx += stride) {
    int ch = idx >> 6, i = idx & 63;
    w2t[idx] = W2[i * 64 + ch];
  }
  for (int idx = t; idx < 128 * 64; idx += stride) {
    int ch = idx >> 6, i = idx & 63;
    w3t[idx] = W3[i * 128 + ch];
  }
}

// ---- kernel 1: FPS — TWO clouds per block (waves 0-3 / 4-7) so each SIMD
//      always has an out-of-phase wave to issue while the other cloud sits in
//      its serial barrier/LDS chain. f32 DPP wave-max + ballot, 4-slot u64
//      exchange per cloud, packed-f32 exact update, in-loop global stores. ----
__global__ __launch_bounds__(FPS_T) void fps_kernel(const float* __restrict__ pos,
                                                    float* __restrict__ selpos_ws,
                                                    float* __restrict__ out_selpos,
                                                    float* __restrict__ out_selbatch) {
  __shared__ float px[2][NP], py[2][NP], pz[2][NP];   // 96 KB
  __shared__ u64 red[2][2][FPS_W];                    // [buf][cloud][wave]
  const int tid = threadIdx.x;
  const int w = tid >> 6, lane = tid & 63;
  const int cl = w >> 2;             // cloud-local id (0/1)
  const int ww = w & 3;              // wave within cloud
  const int ctid = ww * 64 + lane;   // 0..255 within cloud group
  const int b = blockIdx.x * 2 + cl; // global cloud
  const float* pb = pos + (size_t)b * NP * 3;
  for (int i = ctid; i < NP; i += 256) {
    px[cl][i] = pb[i * 3]; py[cl][i] = pb[i * 3 + 1]; pz[cl][i] = pb[i * 3 + 2];
  }
  for (int m = ctid; m < NM; m += 256) out_selbatch[b * NM + m] = (float)b;
  __syncthreads();

  const int pbase = ww * 1024 + lane * 16;   // ascending in lane -> argmax tie ok
  const float p0x = px[cl][0], p0y = py[cl][0], p0z = pz[cl][0];
  v2f mx[8], my[8], mz[8], d[8];
#pragma unroll
  for (int j = 0; j < 8; j++) {
    const int i0 = pbase + 2 * j;
    mx[j] = (v2f){px[cl][i0], px[cl][i0 + 1]};
    my[j] = (v2f){py[cl][i0], py[cl][i0 + 1]};
    mz[j] = (v2f){pz[cl][i0], pz[cl][i0 + 1]};
    d[j] = (v2f){sq3(mx[j].x, my[j].x, mz[j].x, p0x, p0y, p0z),
                 sq3(mx[j].y, my[j].y, mz[j].y, p0x, p0y, p0z)};
  }
  if (ctid == 0) {
    const int o = b * NM * 3;
    selpos_ws[o] = p0x; selpos_ws[o + 1] = p0y; selpos_ws[o + 2] = p0z;
    out_selpos[o] = p0x; out_selpos[o + 1] = p0y; out_selpos[o + 2] = p0z;
  }

  for (int m = 1; m < NM; m++) {
    // local argmax over 16 via index-carrying pairwise tree (>= keeps lower q)
    float tv8[8]; int ti8[8];
#pragma unroll
    for (int j = 0; j < 8; j++) {
      bool g1 = d[j].x >= d[j].y;
      tv8[j] = g1 ? d[j].x : d[j].y;
      ti8[j] = g1 ? 2 * j : 2 * j + 1;
    }
    float tv4[4]; int ti4[4];
#pragma unroll
    for (int j = 0; j < 4; j++) {
      bool g1 = tv8[2 * j] >= tv8[2 * j + 1];
      tv4[j] = g1 ? tv8[2 * j] : tv8[2 * j + 1];
      ti4[j] = g1 ? ti8[2 * j] : ti8[2 * j + 1];
    }
    float tv2[2]; int ti2[2];
#pragma unroll
    for (int j = 0; j < 2; j++) {
      bool g1 = tv4[2 * j] >= tv4[2 * j + 1];
      tv2[j] = g1 ? tv4[2 * j] : tv4[2 * j + 1];
      ti2[j] = g1 ? ti4[2 * j] : ti4[2 * j + 1];
    }
    const bool g0 = tv2[0] >= tv2[1];
    const float bd = g0 ? tv2[0] : tv2[1];
    const int bq = g0 ? ti2[0] : ti2[1];

    // wave max (f32): shr1,2,4,8 + bcast15 + bcast31 -> lane 63
    float wm = bd;
    wm = dpp_maxf<0x111>(wm);
    wm = dpp_maxf<0x112>(wm);
    wm = dpp_maxf<0x114>(wm);
    wm = dpp_maxf<0x118>(wm);
    wm = dpp_maxf<0x142>(wm);
    wm = dpp_maxf<0x143>(wm);
    const u32 wbits = (u32)__builtin_amdgcn_readlane(__float_as_int(wm), 63);
    const float wmax = __int_as_float((int)wbits);
    const u64 msk = __ballot(bd == wmax);
    const int fl = (int)__ffsll((long long)msk) - 1;   // lowest lane = lowest idx
    const int gi = __builtin_amdgcn_readlane(pbase + bq, fl);
    if (lane == 0)
      red[m & 1][cl][ww] = ((u64)wbits << 32) | (u32)(NP - 1 - gi);
    __syncthreads();
    const u64* rs = red[m & 1][cl];
    const u64 g = umax64(umax64(rs[0], rs[1]), umax64(rs[2], rs[3]));
    const int i = NP - 1 - (int)(u32)g;
    const float cx = px[cl][i], cy = py[cl][i], cz = pz[cl][i];
    if (ctid == 0) {
      const int o = (b * NM + m) * 3;
      selpos_ws[o] = cx; selpos_ws[o + 1] = cy; selpos_ws[o + 2] = cz;
      out_selpos[o] = cx; out_selpos[o + 1] = cy; out_selpos[o + 2] = cz;
    }
    // packed exact update (contraction OFF keeps the sq3 rounding sequence)
    {
#pragma clang fp contract(off)
      const v2f Px = (v2f){cx, cx}, Py = (v2f){cy, cy}, Pz = (v2f){cz, cz};
#pragma unroll
      for (int j = 0; j < 8; j++) {
        v2f dx = mx[j] - Px, dy = my[j] - Py, dz = mz[j] - Pz;
        v2f s = ((dx * dx) + (dy * dy)) + (dz * dz);
        d[j] = __builtin_elementwise_min(d[j], s);
      }
    }
  }
}

// ---- kernel 2: radius ball query + exact K-smallest selection ----
__global__ __launch_bounds__(256) void ball_kernel(const float* __restrict__ pos,
                                                   const float* __restrict__ selpos_ws,
                                                   int* __restrict__ nbrp,
                                                   int* __restrict__ cntp) {
  __shared__ u64 keys[CAP];
  __shared__ int scnt;
  const int bm = blockIdx.x, tid = threadIdx.x;
  const int b = bm >> 10;  // NM = 1024
  if (tid == 0) scnt = 0;
  __syncthreads();
  const float sx = selpos_ws[bm * 3], sy = selpos_ws[bm * 3 + 1], sz = selpos_ws[bm * 3 + 2];
  const float* pb = pos + (size_t)b * NP * 3;
  for (int i = tid; i < NP; i += 256) {
    float d2 = sq3(sx, sy, sz, pb[i * 3], pb[i * 3 + 1], pb[i * 3 + 2]);
    if (d2 <= R2C) {
      int s = atomicAdd(&scnt, 1);
      if (s < CAP) keys[s] = ((u64)__float_as_uint(d2) << 32) | (u32)i;
    }
  }
  __syncthreads();
  int C = scnt > CAP ? CAP : scnt;
  for (int s = tid; s < C; s += 256) {
    u64 k = keys[s];
    int r = 0;
    for (int j2 = 0; j2 < C; j2++) r += (keys[j2] < k) ? 1 : 0;
    if (r < NK) nbrp[bm * NK + r] = (int)(k & 0xffffffffu);
  }
  if (tid == 0) cntp[bm] = C < NK ? C : NK;
}

// ---- kernel 3: MLP — LDS-staged gather (1x traffic), 4-acc ILP, LDS exchange ----
#define XP 69   // xs row pad: 69 % 32 = 5 (odd) -> conflict-free column reads
#define HP 65
__global__ __launch_bounds__(256) void mlp_kernel(
    const float* __restrict__ x, const float* __restrict__ pos,
    const float* __restrict__ selpos_ws, const int* __restrict__ nbrp,
    const int* __restrict__ cntp, const float* __restrict__ w1t,
    const float* __restrict__ w2t, const float* __restrict__ w3t,
    const float* __restrict__ b1, const float* __restrict__ b2,
    const float* __restrict__ b3, float* __restrict__ out) {
  __shared__ float arena[64 * XP + 64 * HP];
  float* xs = arena;
  float* h1s = arena + 64 * XP;
  float* h2s = arena;
  float* h3s = arena;
  const int pm = blockIdx.x, tid = threadIdx.x;
  const int n = tid & 63;
  const int w = __builtin_amdgcn_readfirstlane(tid >> 6);
  const int b = pm >> 10;
  const int c = cntp[pm];
  const float NEGINF = -__builtin_inff();

  {
    const int r = tid >> 2, p = tid & 3;
    const int jr = (r < c) ? nbrp[pm * NK + r] : 0;
    const float* xr = x + ((size_t)b * NP + jr) * NF + p * 16;
#pragma unroll
    for (int f = 0; f < 4; f++) {
      const float4 v = *(const float4*)(xr + f * 4);
      float* dst = xs + r * XP + p * 16 + f * 4;
      dst[0] = v.x; dst[1] = v.y; dst[2] = v.z; dst[3] = v.w;
    }
    if (p == 0) {
      const float* pr = pos + ((size_t)b * NP + jr) * 3;
      xs[r * XP + 64] = pr[0] - selpos_ws[pm * 3];
      xs[r * XP + 65] = pr[1] - selpos_ws[pm * 3 + 1];
      xs[r * XP + 66] = pr[2] - selpos_ws[pm * 3 + 2];
    }
  }
  __syncthreads();
  float h0[67];
#pragma unroll
  for (int i = 0; i < 67; ++i) h0[i] = xs[n * XP + i];
  const int cb1 = w * 16;
#pragma unroll
  for (int g = 0; g < 4; ++g) {
    const int ch = cb1 + g * 4;
    float a0 = b1[ch], a1 = b1[ch + 1], a2 = b1[ch + 2], a3 = b1[ch + 3];
    const float* w0 = w1t + ch * 67;
    const float* w1 = w0 + 67;
    const float* w2 = w1 + 67;
    const float* w3 = w2 + 67;
#pragma unroll
    for (int i = 0; i < 67; ++i) {
      const float h = h0[i];
      a0 = fmaf(h, w0[i], a0); a1 = fmaf(h, w1[i], a1);
      a2 = fmaf(h, w2[i], a2); a3 = fmaf(h, w3[i], a3);
    }
    h1s[n * HP + ch] = fmaxf(a0, 0.f);
    h1s[n * HP + ch + 1] = fmaxf(a1, 0.f);
    h1s[n * HP + ch + 2] = fmaxf(a2, 0.f);
    h1s[n * HP + ch + 3] = fmaxf(a3, 0.f);
  }
  __syncthreads();
  float h1r[64];
#pragma unroll
  for (int i = 0; i < 64; ++i) h1r[i] = h1s[n * HP + i];
#pragma unroll
  for (int g = 0; g < 4; ++g) {
    const int ch = cb1 + g * 4;
    float a0 = b2[ch], a1 = b2[ch + 1], a2 = b2[ch + 2], a3 = b2[ch + 3];
    const float* w0 = w2t + ch * 64;
    const float* w1 = w0 + 64;
    const float* w2 = w1 + 64;
    const float* w3 = w2 + 64;
#pragma unroll
    for (int i = 0; i < 64; ++i) {
      const float h = h1r[i];
      a0 = fmaf(h, w0[i], a0); a1 = fmaf(h, w1[i], a1);
      a2 = fmaf(h, w2[i], a2); a3 = fmaf(h, w3[i], a3);
    }
    h2s[n * HP + ch] = fmaxf(a0, 0.f);
    h2s[n * HP + ch + 1] = fmaxf(a1, 0.f);
    h2s[n * HP + ch + 2] = fmaxf(a2, 0.f);
    h2s[n * HP + ch + 3] = fmaxf(a3, 0.f);
  }
  __syncthreads();
  float h2r[64];
#pragma unroll
  for (int i = 0; i < 64; ++i) h2r[i] = h2s[n * HP + i];
  __syncthreads();
  const bool valid = n < c;
  const int cb3 = w * 32;
#pragma unroll
  for (int g = 0; g < 8; ++g) {
    const int ch = cb3 + g * 4;
    float a0 = b3[ch], a1 = b3[ch + 1], a2 = b3[ch + 2], a3 = b3[ch + 3];
    const float* w0 = w3t + ch * 64;
    const float* w1 = w0 + 64;
    const float* w2 = w1 + 64;
    const float* w3 = w2 + 64;
#pragma unroll
    for (int i = 0; i < 64; ++i) {
      const float h = h2r[i];
      a0 = fmaf(h, w0[i], a0); a1 = fmaf(h, w1[i], a1);
      a2 = fmaf(h, w2[i], a2); a3 = fmaf(h, w3[i], a3);
    }
    h3s[(ch) * HP + n] = valid ? fmaxf(a0, 0.f) : NEGINF;
    h3s[(ch + 1) * HP + n] = valid ? fmaxf(a1, 0.f) : NEGINF;
    h3s[(ch + 2) * HP + n] = valid ? fmaxf(a2, 0.f) : NEGINF;
    h3s[(ch + 3) * HP + n] = valid ? fmaxf(a3, 0.f) : NEGINF;
  }
  __syncthreads();
  if (tid < 128) {
    float m0 = NEGINF;
#pragma unroll
    for (int i = 0; i < 64; ++i) m0 = fmaxf(m0, h3s[tid * HP + i]);
    out[(size_t)pm * NOUT + tid] = (c == 0) ? 0.f : m0;
  }
}

extern "C" void kernel_launch(void* const* d_in, const int* in_sizes, int n_in,
                              void* d_out, int out_size, void* d_ws, size_t ws_size,
                              hipStream_t stream) {
  const float* x   = (const float*)d_in[0];
  const float* pos = (const float*)d_in[1];
  const float* W1 = (const float*)d_in[3];
  const float* b1 = (const float*)d_in[4];
  const float* W2 = (const float*)d_in[5];
  const float* b2 = (const float*)d_in[6];
  const float* W3 = (const float*)d_in[7];
  const float* b3 = (const float*)d_in[8];

  float* out          = (float*)d_out;
  float* out_selpos   = out + (size_t)NB * NM * NOUT;
  float* out_selbatch = out_selpos + (size_t)NB * NM * 3;

  int* ws_i = (int*)d_ws;
  float* ws_f = (float*)d_ws;
  int* cntp     = ws_i + 8192;
  int* nbrp     = ws_i + 16384;
  float* selpos = ws_f + 540672;
  float* w1t    = ws_f + 565248;
  float* w2t    = ws_f + 569536;
  float* w3t    = ws_f + 573632;

  hipLaunchKernelGGL(prep_weights, dim3(34), dim3(256), 0, stream, W1, W2, W3, w1t, w2t, w3t);
  hipLaunchKernelGGL(fps_kernel, dim3(NB / 2), dim3(FPS_T), 0, stream, pos, selpos, out_selpos, out_selbatch);
  hipLaunchKernelGGL(ball_kernel, dim3(NB * NM), dim3(256), 0, stream, pos, selpos, nbrp, cntp);
  hipLaunchKernelGGL(mlp_kernel, dim3(NB * NM), dim3(256), 0, stream,
                     x, pos, selpos, nbrp, cntp, w1t, w2t, w3t, b1, b2, b3, out);
}

// Round 9
// 1202.337 us; speedup vs baseline: 1.3509x; 1.3509x over previous
//
#include <hip/hip_runtime.h>
#include <cstdint>

typedef unsigned long long u64;
typedef unsigned int u32;
typedef float v2f __attribute__((ext_vector_type(2)));

#define NB 8
#define NP 4096
#define NK 64
#define NM 1024
#define NF 64
#define NOUT 128
#define R2C 0.04f      // float(0.2*0.2 in double) == 0x3D23D70A
#define CAP 2048
#define FPS_T 512
#define FPS_Q 8        // 4 float2 pairs per lane
#define TAG_INIT 0xFFFFF000u

// Exact (non-contracted) squared distance, left-to-right sum, matching XLA's
// elementwise (a-b)**2 then reduce over the size-3 axis.
static __device__ __forceinline__ float sq3(float ax, float ay, float az,
                                            float bx, float by, float bz) {
  float dx = __fsub_rn(ax, bx), dy = __fsub_rn(ay, by), dz = __fsub_rn(az, bz);
  return __fadd_rn(__fadd_rn(__fmul_rn(dx, dx), __fmul_rn(dy, dy)), __fmul_rn(dz, dz));
}

// f32 max with a DPP-shifted copy; bound_ctrl=1 feeds 0.0f (safe: d2 >= 0)
template <int CTRL>
static __device__ __forceinline__ float dpp_maxf(float x) {
  int m = __builtin_amdgcn_update_dpp(0, __float_as_int(x), CTRL, 0xf, 0xf, true);
  return fmaxf(x, __int_as_float(m));
}

static __device__ __forceinline__ u64 umax64(u64 a, u64 b) { return a > b ? a : b; }

// ---- kernel 0: transpose weights into ws (ch-major rows -> uniform s_load) ----
__global__ void prep_weights(const float* __restrict__ W1, const float* __restrict__ W2,
                             const float* __restrict__ W3,
                             float* __restrict__ w1t, float* __restrict__ w2t,
                             float* __restrict__ w3t) {
  int t = blockIdx.x * blockDim.x + threadIdx.x;
  int stride = gridDim.x * blockDim.x;
  for (int idx = t; idx < 64 * 67; idx += stride) {
    int ch = idx / 67, i = idx - ch * 67;
    w1t[idx] = W1[i * 64 + ch];
  }
  for (int idx = t; idx < 64 * 64; idx += stride) {
    int ch = idx >> 6, i = idx & 63;
    w2t[idx] = W2[i * 64 + ch];
  }
  for (int idx = t; idx < 128 * 64; idx += stride) {
    int ch = idx >> 6, i = idx & 63;
    w3t[idx] = W3[i * 128 + ch];
  }
}

// ---- kernel 1: FPS — NO barrier in the loop. 8 waves exchange per-wave max
//      keys through tag-stamped LDS slots (double-buffered, spin on tag).
//      key = (f32bits << 32) | (m << 12) | (NP-1-idx). Max skew between waves
//      is <= 2 iterations (each wave must see all tags of iter m before
//      writing iter m+1), so the 2-deep buffer is race-free. ----
__global__ __launch_bounds__(FPS_T) void fps_kernel(const float* __restrict__ pos,
                                                    float* __restrict__ selpos_ws,
                                                    float* __restrict__ out_selpos,
                                                    float* __restrict__ out_selbatch) {
  __shared__ float4 pxyz[NP];   // 64 KB
  __shared__ u64 red[2][8];
  const int b = blockIdx.x, tid = threadIdx.x;
  const float* pb = pos + (size_t)b * NP * 3;
  for (int i = tid; i < NP; i += FPS_T)
    pxyz[i] = make_float4(pb[i * 3], pb[i * 3 + 1], pb[i * 3 + 2], 0.f);
  for (int m = tid; m < NM; m += FPS_T) out_selbatch[b * NM + m] = (float)b;
  if (tid < 16) ((u64*)red)[tid] = (u64)TAG_INIT;  // tag 0xFFFFF != any m
  __syncthreads();  // the only barrier: pxyz + red-init visible to all waves

  v2f mx[4], my[4], mz[4], d[4];
  const float4 p0 = pxyz[0];
#pragma unroll
  for (int j = 0; j < 4; j++) {
    const float4 A = pxyz[tid * FPS_Q + 2 * j];
    const float4 B = pxyz[tid * FPS_Q + 2 * j + 1];
    mx[j] = (v2f){A.x, B.x}; my[j] = (v2f){A.y, B.y}; mz[j] = (v2f){A.z, B.z};
    d[j] = (v2f){sq3(A.x, A.y, A.z, p0.x, p0.y, p0.z),
                 sq3(B.x, B.y, B.z, p0.x, p0.y, p0.z)};
  }
  if (tid == 0) {
    const int o = b * NM * 3;
    selpos_ws[o] = p0.x; selpos_ws[o + 1] = p0.y; selpos_ws[o + 2] = p0.z;
    out_selpos[o] = p0.x; out_selpos[o + 1] = p0.y; out_selpos[o + 2] = p0.z;
  }
  const int lane = tid & 63, w = tid >> 6;

  for (int m = 1; m < NM; m++) {
    // local argmax over 8 via index-carrying pairwise tree (>= keeps lower q)
    float dv[8];
#pragma unroll
    for (int j = 0; j < 4; j++) { dv[2 * j] = d[j].x; dv[2 * j + 1] = d[j].y; }
    float tv4[4]; int ti4[4];
#pragma unroll
    for (int j = 0; j < 4; j++) {
      bool g1 = dv[2 * j] >= dv[2 * j + 1];
      tv4[j] = g1 ? dv[2 * j] : dv[2 * j + 1];
      ti4[j] = g1 ? 2 * j : 2 * j + 1;
    }
    float tv2[2]; int ti2[2];
#pragma unroll
    for (int j = 0; j < 2; j++) {
      bool g1 = tv4[2 * j] >= tv4[2 * j + 1];
      tv2[j] = g1 ? tv4[2 * j] : tv4[2 * j + 1];
      ti2[j] = g1 ? ti4[2 * j] : ti4[2 * j + 1];
    }
    const bool g0 = tv2[0] >= tv2[1];
    const float bd = g0 ? tv2[0] : tv2[1];
    const int bq = g0 ? ti2[0] : ti2[1];

    // wave max (f32): shr1,2,4,8 + bcast15 + bcast31 -> lane 63
    float wm = bd;
    wm = dpp_maxf<0x111>(wm);
    wm = dpp_maxf<0x112>(wm);
    wm = dpp_maxf<0x114>(wm);
    wm = dpp_maxf<0x118>(wm);
    wm = dpp_maxf<0x142>(wm);
    wm = dpp_maxf<0x143>(wm);
    const u32 wbits = (u32)__builtin_amdgcn_readlane(__float_as_int(wm), 63);
    const float wmax = __int_as_float((int)wbits);
    const u64 msk = __ballot(bd == wmax);
    const int fl = (int)__ffsll((long long)msk) - 1;   // lowest lane = lowest idx
    const int gi = __builtin_amdgcn_readlane(tid * FPS_Q + bq, fl);
    if (lane == 0)
      __hip_atomic_store(&red[m & 1][w],
                         ((u64)wbits << 32) | ((u32)m << 12) | (u32)(NP - 1 - gi),
                         __ATOMIC_RELAXED, __HIP_MEMORY_SCOPE_WORKGROUP);
    // spin until all 8 slots carry tag m (no s_barrier, no waitcnt drain)
    u64 v0, v1, v2, v3, v4, v5, v6, v7;
    bool ok;
    do {
      v0 = __hip_atomic_load(&red[m & 1][0], __ATOMIC_RELAXED, __HIP_MEMORY_SCOPE_WORKGROUP);
      v1 = __hip_atomic_load(&red[m & 1][1], __ATOMIC_RELAXED, __HIP_MEMORY_SCOPE_WORKGROUP);
      v2 = __hip_atomic_load(&red[m & 1][2], __ATOMIC_RELAXED, __HIP_MEMORY_SCOPE_WORKGROUP);
      v3 = __hip_atomic_load(&red[m & 1][3], __ATOMIC_RELAXED, __HIP_MEMORY_SCOPE_WORKGROUP);
      v4 = __hip_atomic_load(&red[m & 1][4], __ATOMIC_RELAXED, __HIP_MEMORY_SCOPE_WORKGROUP);
      v5 = __hip_atomic_load(&red[m & 1][5], __ATOMIC_RELAXED, __HIP_MEMORY_SCOPE_WORKGROUP);
      v6 = __hip_atomic_load(&red[m & 1][6], __ATOMIC_RELAXED, __HIP_MEMORY_SCOPE_WORKGROUP);
      v7 = __hip_atomic_load(&red[m & 1][7], __ATOMIC_RELAXED, __HIP_MEMORY_SCOPE_WORKGROUP);
      const u32 t01 = ((u32)v0 >> 12) & ((u32)v1 >> 12);
      const u32 t23 = ((u32)v2 >> 12) & ((u32)v3 >> 12);
      const u32 t45 = ((u32)v4 >> 12) & ((u32)v5 >> 12);
      const u32 t67 = ((u32)v6 >> 12) & ((u32)v7 >> 12);
      const u32 to01 = ((u32)v0 >> 12) | ((u32)v1 >> 12);
      const u32 to23 = ((u32)v2 >> 12) | ((u32)v3 >> 12);
      const u32 to45 = ((u32)v4 >> 12) | ((u32)v5 >> 12);
      const u32 to67 = ((u32)v6 >> 12) | ((u32)v7 >> 12);
      // all tags == m  <=>  AND == m and OR == m
      ok = ((t01 & t23 & t45 & t67) == (u32)m) &&
           ((to01 | to23 | to45 | to67) == (u32)m);
    } while (!ok);
    const u64 g = umax64(umax64(umax64(v0, v1), umax64(v2, v3)),
                         umax64(umax64(v4, v5), umax64(v6, v7)));
    const int i = NP - 1 - (int)(g & 0xFFFu);
    const float4 P = pxyz[i];
    if (tid == 0) {
      const int o = (b * NM + m) * 3;
      selpos_ws[o] = P.x; selpos_ws[o + 1] = P.y; selpos_ws[o + 2] = P.z;
      out_selpos[o] = P.x; out_selpos[o + 1] = P.y; out_selpos[o + 2] = P.z;
    }
    // packed exact update (contraction OFF keeps the sq3 rounding sequence)
    {
#pragma clang fp contract(off)
      const v2f Px = (v2f){P.x, P.x}, Py = (v2f){P.y, P.y}, Pz = (v2f){P.z, P.z};
#pragma unroll
      for (int j = 0; j < 4; j++) {
        v2f dx = mx[j] - Px, dy = my[j] - Py, dz = mz[j] - Pz;
        v2f s = ((dx * dx) + (dy * dy)) + (dz * dz);
        d[j] = __builtin_elementwise_min(d[j], s);
      }
    }
  }
}

// ---- kernel 2: radius ball query + exact K-smallest selection ----
__global__ __launch_bounds__(256) void ball_kernel(const float* __restrict__ pos,
                                                   const float* __restrict__ selpos_ws,
                                                   int* __restrict__ nbrp,
                                                   int* __restrict__ cntp) {
  __shared__ u64 keys[CAP];
  __shared__ int scnt;
  const int bm = blockIdx.x, tid = threadIdx.x;
  const int b = bm >> 10;  // NM = 1024
  if (tid == 0) scnt = 0;
  __syncthreads();
  const float sx = selpos_ws[bm * 3], sy = selpos_ws[bm * 3 + 1], sz = selpos_ws[bm * 3 + 2];
  const float* pb = pos + (size_t)b * NP * 3;
  for (int i = tid; i < NP; i += 256) {
    float d2 = sq3(sx, sy, sz, pb[i * 3], pb[i * 3 + 1], pb[i * 3 + 2]);
    if (d2 <= R2C) {
      int s = atomicAdd(&scnt, 1);
      if (s < CAP) keys[s] = ((u64)__float_as_uint(d2) << 32) | (u32)i;
    }
  }
  __syncthreads();
  int C = scnt > CAP ? CAP : scnt;
  for (int s = tid; s < C; s += 256) {
    u64 k = keys[s];
    int r = 0;
    for (int j2 = 0; j2 < C; j2++) r += (keys[j2] < k) ? 1 : 0;
    if (r < NK) nbrp[bm * NK + r] = (int)(k & 0xffffffffu);
  }
  if (tid == 0) cntp[bm] = C < NK ? C : NK;
}

// ---- kernel 3: MLP — LDS-staged gather (1x traffic), 4-acc ILP, LDS exchange ----
#define XP 69   // xs row pad: 69 % 32 = 5 (odd) -> conflict-free column reads
#define HP 65
__global__ __launch_bounds__(256) void mlp_kernel(
    const float* __restrict__ x, const float* __restrict__ pos,
    const float* __restrict__ selpos_ws, const int* __restrict__ nbrp,
    const int* __restrict__ cntp, const float* __restrict__ w1t,
    const float* __restrict__ w2t, const float* __restrict__ w3t,
    const float* __restrict__ b1, const float* __restrict__ b2,
    const float* __restrict__ b3, float* __restrict__ out) {
  __shared__ float arena[64 * XP + 64 * HP];
  float* xs = arena;
  float* h1s = arena + 64 * XP;
  float* h2s = arena;
  float* h3s = arena;
  const int pm = blockIdx.x, tid = threadIdx.x;
  const int n = tid & 63;
  const int w = __builtin_amdgcn_readfirstlane(tid >> 6);
  const int b = pm >> 10;
  const int c = cntp[pm];
  const float NEGINF = -__builtin_inff();

  {
    const int r = tid >> 2, p = tid & 3;
    const int jr = (r < c) ? nbrp[pm * NK + r] : 0;
    const float* xr = x + ((size_t)b * NP + jr) * NF + p * 16;
#pragma unroll
    for (int f = 0; f < 4; f++) {
      const float4 v = *(const float4*)(xr + f * 4);
      float* dst = xs + r * XP + p * 16 + f * 4;
      dst[0] = v.x; dst[1] = v.y; dst[2] = v.z; dst[3] = v.w;
    }
    if (p == 0) {
      const float* pr = pos + ((size_t)b * NP + jr) * 3;
      xs[r * XP + 64] = pr[0] - selpos_ws[pm * 3];
      xs[r * XP + 65] = pr[1] - selpos_ws[pm * 3 + 1];
      xs[r * XP + 66] = pr[2] - selpos_ws[pm * 3 + 2];
    }
  }
  __syncthreads();
  float h0[67];
#pragma unroll
  for (int i = 0; i < 67; ++i) h0[i] = xs[n * XP + i];
  const int cb1 = w * 16;
#pragma unroll
  for (int g = 0; g < 4; ++g) {
    const int ch = cb1 + g * 4;
    float a0 = b1[ch], a1 = b1[ch + 1], a2 = b1[ch + 2], a3 = b1[ch + 3];
    const float* w0 = w1t + ch * 67;
    const float* w1 = w0 + 67;
    const float* w2 = w1 + 67;
    const float* w3 = w2 + 67;
#pragma unroll
    for (int i = 0; i < 67; ++i) {
      const float h = h0[i];
      a0 = fmaf(h, w0[i], a0); a1 = fmaf(h, w1[i], a1);
      a2 = fmaf(h, w2[i], a2); a3 = fmaf(h, w3[i], a3);
    }
    h1s[n * HP + ch] = fmaxf(a0, 0.f);
    h1s[n * HP + ch + 1] = fmaxf(a1, 0.f);
    h1s[n * HP + ch + 2] = fmaxf(a2, 0.f);
    h1s[n * HP + ch + 3] = fmaxf(a3, 0.f);
  }
  __syncthreads();
  float h1r[64];
#pragma unroll
  for (int i = 0; i < 64; ++i) h1r[i] = h1s[n * HP + i];
#pragma unroll
  for (int g = 0; g < 4; ++g) {
    const int ch = cb1 + g * 4;
    float a0 = b2[ch], a1 = b2[ch + 1], a2 = b2[ch + 2], a3 = b2[ch + 3];
    const float* w0 = w2t + ch * 64;
    const float* w1 = w0 + 64;
    const float* w2 = w1 + 64;
    const float* w3 = w2 + 64;
#pragma unroll
    for (int i = 0; i < 64; ++i) {
      const float h = h1r[i];
      a0 = fmaf(h, w0[i], a0); a1 = fmaf(h, w1[i], a1);
      a2 = fmaf(h, w2[i], a2); a3 = fmaf(h, w3[i], a3);
    }
    h2s[n * HP + ch] = fmaxf(a0, 0.f);
    h2s[n * HP + ch + 1] = fmaxf(a1, 0.f);
    h2s[n * HP + ch + 2] = fmaxf(a2, 0.f);
    h2s[n * HP + ch + 3] = fmaxf(a3, 0.f);
  }
  __syncthreads();
  float h2r[64];
#pragma unroll
  for (int i = 0; i < 64; ++i) h2r[i] = h2s[n * HP + i];
  __syncthreads();
  const bool valid = n < c;
  const int cb3 = w * 32;
#pragma unroll
  for (int g = 0; g < 8; ++g) {
    const int ch = cb3 + g * 4;
    float a0 = b3[ch], a1 = b3[ch + 1], a2 = b3[ch + 2], a3 = b3[ch + 3];
    const float* w0 = w3t + ch * 64;
    const float* w1 = w0 + 64;
    const float* w2 = w1 + 64;
    const float* w3 = w2 + 64;
#pragma unroll
    for (int i = 0; i < 64; ++i) {
      const float h = h2r[i];
      a0 = fmaf(h, w0[i], a0); a1 = fmaf(h, w1[i], a1);
      a2 = fmaf(h, w2[i], a2); a3 = fmaf(h, w3[i], a3);
    }
    h3s[(ch) * HP + n] = valid ? fmaxf(a0, 0.f) : NEGINF;
    h3s[(ch + 1) * HP + n] = valid ? fmaxf(a1, 0.f) : NEGINF;
    h3s[(ch + 2) * HP + n] = valid ? fmaxf(a2, 0.f) : NEGINF;
    h3s[(ch + 3) * HP + n] = valid ? fmaxf(a3, 0.f) : NEGINF;
  }
  __syncthreads();
  if (tid < 128) {
    float m0 = NEGINF;
#pragma unroll
    for (int i = 0; i < 64; ++i) m0 = fmaxf(m0, h3s[tid * HP + i]);
    out[(size_t)pm * NOUT + tid] = (c == 0) ? 0.f : m0;
  }
}

extern "C" void kernel_launch(void* const* d_in, const int* in_sizes, int n_in,
                              void* d_out, int out_size, void* d_ws, size_t ws_size,
                              hipStream_t stream) {
  const float* x   = (const float*)d_in[0];
  const float* pos = (const float*)d_in[1];
  const float* W1 = (const float*)d_in[3];
  const float* b1 = (const float*)d_in[4];
  const float* W2 = (const float*)d_in[5];
  const float* b2 = (const float*)d_in[6];
  const float* W3 = (const float*)d_in[7];
  const float* b3 = (const float*)d_in[8];

  float* out          = (float*)d_out;
  float* out_selpos   = out + (size_t)NB * NM * NOUT;
  float* out_selbatch = out_selpos + (size_t)NB * NM * 3;

  int* ws_i = (int*)d_ws;
  float* ws_f = (float*)d_ws;
  int* cntp     = ws_i + 8192;
  int* nbrp     = ws_i + 16384;
  float* selpos = ws_f + 540672;
  float* w1t    = ws_f + 565248;
  float* w2t    = ws_f + 569536;
  float* w3t    = ws_f + 573632;

  hipLaunchKernelGGL(prep_weights, dim3(34), dim3(256), 0, stream, W1, W2, W3, w1t, w2t, w3t);
  hipLaunchKernelGGL(fps_kernel, dim3(NB), dim3(FPS_T), 0, stream, pos, selpos, out_selpos, out_selbatch);
  hipLaunchKernelGGL(ball_kernel, dim3(NB * NM), dim3(256), 0, stream, pos, selpos, nbrp, cntp);
  hipLaunchKernelGGL(mlp_kernel, dim3(NB * NM), dim3(256), 0, stream,
                     x, pos, selpos, nbrp, cntp, w1t, w2t, w3t, b1, b2, b3, out);
}

// Round 12
// 1126.463 us; speedup vs baseline: 1.4419x; 1.0674x over previous
//
#include <hip/hip_runtime.h>
#include <cstdint>

typedef unsigned long long u64;
typedef unsigned int u32;

#define NB 8
#define NP 4096
#define NK 64
#define NM 1024
#define NF 64
#define NOUT 128
#define R2C 0.04f      // float(0.2*0.2 in double) == 0x3D23D70A
#define CAP 2048
#define FPS_T 512
#define FPS_Q 8

// Exact (non-contracted) squared distance, left-to-right sum, matching XLA's
// elementwise (a-b)**2 then reduce over the size-3 axis.
static __device__ __forceinline__ float sq3(float ax, float ay, float az,
                                            float bx, float by, float bz) {
  float dx = __fsub_rn(ax, bx), dy = __fsub_rn(ay, by), dz = __fsub_rn(az, bz);
  return __fadd_rn(__fadd_rn(__fmul_rn(dx, dx), __fmul_rn(dy, dy)), __fmul_rn(dz, dz));
}

// f32 max with a DPP-shifted copy; bound_ctrl=1 feeds 0.0f (safe: d2 >= 0)
template <int CTRL>
static __device__ __forceinline__ float dpp_maxf(float x) {
  int m = __builtin_amdgcn_update_dpp(0, __float_as_int(x), CTRL, 0xf, 0xf, true);
  return fmaxf(x, __int_as_float(m));
}

static __device__ __forceinline__ u64 umax64(u64 a, u64 b) { return a > b ? a : b; }

// ---- kernel 0: transpose weights into ws (ch-major rows -> uniform s_load) ----
__global__ void prep_weights(const float* __restrict__ W1, const float* __restrict__ W2,
                             const float* __restrict__ W3,
                             float* __restrict__ w1t, float* __restrict__ w2t,
                             float* __restrict__ w3t) {
  int t = blockIdx.x * blockDim.x + threadIdx.x;
  int stride = gridDim.x * blockDim.x;
  for (int idx = t; idx < 64 * 67; idx += stride) {
    int ch = idx / 67, i = idx - ch * 67;
    w1t[idx] = W1[i * 64 + ch];
  }
  for (int idx = t; idx < 64 * 64; idx += stride) {
    int ch = idx >> 6, i = idx & 63;
    w2t[idx] = W2[i * 64 + ch];
  }
  for (int idx = t; idx < 128 * 64; idx += stride) {
    int ch = idx >> 6, i = idx & 63;
    w3t[idx] = W3[i * 128 + ch];
  }
}

// ---- kernel 1: FPS — r3 champion structure (512t, Q=8, f32 DPP wave-max +
//      ballot, 8-slot u64 exchange, 1 barrier/iter, SCALAR update). Single
//      delta vs r3: selected positions buffered in LDS and flushed at the end,
//      so no global-store vmcnt drain inside the loop's barrier. ----
__global__ __launch_bounds__(FPS_T) void fps_kernel(const float* __restrict__ pos,
                                                    float* __restrict__ selpos_ws,
                                                    float* __restrict__ out_selpos,
                                                    float* __restrict__ out_selbatch) {
  __shared__ float4 pxyz[NP];   // 64 KB
  __shared__ float4 sel[NM];    // 16 KB, flushed at end
  __shared__ u64 red[2][8];
  const int b = blockIdx.x, tid = threadIdx.x;
  const float* pb = pos + (size_t)b * NP * 3;
  for (int i = tid; i < NP; i += FPS_T)
    pxyz[i] = make_float4(pb[i * 3], pb[i * 3 + 1], pb[i * 3 + 2], 0.f);
  for (int m = tid; m < NM; m += FPS_T) out_selbatch[b * NM + m] = (float)b;
  __syncthreads();

  float mx[FPS_Q], my[FPS_Q], mz[FPS_Q], d[FPS_Q];
  const float4 p0 = pxyz[0];
#pragma unroll
  for (int q = 0; q < FPS_Q; q++) {
    const float4 P = pxyz[tid * FPS_Q + q];
    mx[q] = P.x; my[q] = P.y; mz[q] = P.z;
    d[q] = sq3(P.x, P.y, P.z, p0.x, p0.y, p0.z);
  }
  if (tid == 0) sel[0] = p0;
  const int lane = tid & 63, w = tid >> 6;
  for (int m = 1; m < NM; m++) {
    // per-lane argmax over 8 (strict > keeps lowest q -> lowest global idx)
    float bd = d[0]; int bq = 0;
#pragma unroll
    for (int q = 1; q < FPS_Q; q++) {
      bool g = d[q] > bd;
      bd = g ? d[q] : bd; bq = g ? q : bq;
    }
    // wave max (f32): shr1,2,4,8 + bcast15 + bcast31 -> lane 63
    float wm = bd;
    wm = dpp_maxf<0x111>(wm);
    wm = dpp_maxf<0x112>(wm);
    wm = dpp_maxf<0x114>(wm);
    wm = dpp_maxf<0x118>(wm);
    wm = dpp_maxf<0x142>(wm);
    wm = dpp_maxf<0x143>(wm);
    const u32 wbits = (u32)__builtin_amdgcn_readlane(__float_as_int(wm), 63);
    const float wmax = __int_as_float((int)wbits);
    // lowest lane holding the max; its candidate idx (lane order == idx order)
    const u64 msk = __ballot(bd == wmax);
    const int fl = (int)__ffsll((long long)msk) - 1;
    const int il = __builtin_amdgcn_readlane(tid * FPS_Q + bq, fl);
    if (lane == 0)
      red[m & 1][w] = ((u64)wbits << 32) | (u32)(NP - 1 - il);
    __syncthreads();
    // all lanes: broadcast-read 8 slots, tree max
    const u64* rs = red[m & 1];
    u64 g = umax64(umax64(umax64(rs[0], rs[1]), umax64(rs[2], rs[3])),
                   umax64(umax64(rs[4], rs[5]), umax64(rs[6], rs[7])));
    const int i = NP - 1 - (int)(u32)g;
    const float4 P = pxyz[i];
    if (tid == 0) sel[m] = P;
#pragma unroll
    for (int q = 0; q < FPS_Q; q++)
      d[q] = fminf(d[q], sq3(mx[q], my[q], mz[q], P.x, P.y, P.z));
  }
  __syncthreads();
  for (int m = tid; m < NM; m += FPS_T) {
    const float4 P = sel[m];
    const int o = (b * NM + m) * 3;
    selpos_ws[o] = P.x; selpos_ws[o + 1] = P.y; selpos_ws[o + 2] = P.z;
    out_selpos[o] = P.x; out_selpos[o + 1] = P.y; out_selpos[o + 2] = P.z;
  }
}

// ---- kernel 2: FUSED ball query + MLP + max-pool. Ball keys live in LDS
//      overlaying the MLP staging arena (keys die before staging overwrites
//      them); neighbor list + count pass through LDS, no global round-trip. ----
#define XP 69   // xs row pad: 69 % 32 = 5 (odd) -> conflict-free column reads
#define HP 65
__global__ __launch_bounds__(256) void ballmlp_kernel(
    const float* __restrict__ x, const float* __restrict__ pos,
    const float* __restrict__ selpos_ws, const float* __restrict__ w1t,
    const float* __restrict__ w2t, const float* __restrict__ w3t,
    const float* __restrict__ b1, const float* __restrict__ b2,
    const float* __restrict__ b3, float* __restrict__ out) {
  // arena: bytes 0..16383 = ball keys[2048] (dead after selection);
  //        xs=[64][69] @0; h1=[64][65] @4416f; h2=[64][65] @0; h3=[128][65] @0
  __shared__ alignas(16) float arena[64 * XP + 64 * HP];
  __shared__ int nbr_s[NK];
  __shared__ int scnt, c_s;
  u64* keys = (u64*)arena;
  float* xs = arena;
  float* h1s = arena + 64 * XP;
  float* h2s = arena;
  float* h3s = arena;
  const int pm = blockIdx.x, tid = threadIdx.x;
  const int b = pm >> 10;  // NM = 1024
  const float NEGINF = -__builtin_inff();

  // ---- phase A: radius ball query ----
  if (tid == 0) scnt = 0;
  if (tid < NK) nbr_s[tid] = 0;
  __syncthreads();
  const float sx = selpos_ws[pm * 3], sy = selpos_ws[pm * 3 + 1], sz = selpos_ws[pm * 3 + 2];
  const float* pb = pos + (size_t)b * NP * 3;
  for (int i = tid; i < NP; i += 256) {
    float d2 = sq3(sx, sy, sz, pb[i * 3], pb[i * 3 + 1], pb[i * 3 + 2]);
    if (d2 <= R2C) {
      int s = atomicAdd(&scnt, 1);
      if (s < CAP) keys[s] = ((u64)__float_as_uint(d2) << 32) | (u32)i;
    }
  }
  __syncthreads();
  const int C = scnt > CAP ? CAP : scnt;
  // exact rank selection: keys unique (idx in low bits) -> ranks unique
  for (int s = tid; s < C; s += 256) {
    u64 k = keys[s];
    int r = 0;
    for (int j2 = 0; j2 < C; j2++) r += (keys[j2] < k) ? 1 : 0;
    if (r < NK) nbr_s[r] = (int)(k & 0xffffffffu);
  }
  if (tid == 0) c_s = C < NK ? C : NK;
  __syncthreads();  // keys reads done; nbr_s/c_s visible

  // ---- phase B: MLP ----
  const int c = c_s;
  const int n = tid & 63;
  const int w = __builtin_amdgcn_readfirstlane(tid >> 6);
  // cooperative gather: thread t stages quarter (t&3) of row (t>>2)
  {
    const int r = tid >> 2, p = tid & 3;
    const int jr = (r < c) ? nbr_s[r] : 0;
    const float* xr = x + ((size_t)b * NP + jr) * NF + p * 16;
#pragma unroll
    for (int f = 0; f < 4; f++) {
      const float4 v = *(const float4*)(xr + f * 4);
      float* dst = xs + r * XP + p * 16 + f * 4;
      dst[0] = v.x; dst[1] = v.y; dst[2] = v.z; dst[3] = v.w;
    }
    if (p == 0) {
      const float* pr = pos + ((size_t)b * NP + jr) * 3;
      xs[r * XP + 64] = pr[0] - sx;
      xs[r * XP + 65] = pr[1] - sy;
      xs[r * XP + 66] = pr[2] - sz;
    }
  }
  __syncthreads();
  float h0[67];
#pragma unroll
  for (int i = 0; i < 67; ++i) h0[i] = xs[n * XP + i];
  const int cb1 = w * 16;
#pragma unroll
  for (int g = 0; g < 4; ++g) {
    const int ch = cb1 + g * 4;
    float a0 = b1[ch], a1 = b1[ch + 1], a2 = b1[ch + 2], a3 = b1[ch + 3];
    const float* w0 = w1t + ch * 67;
    const float* w1 = w0 + 67;
    const float* w2 = w1 + 67;
    const float* w3 = w2 + 67;
#pragma unroll
    for (int i = 0; i < 67; ++i) {
      const float h = h0[i];
      a0 = fmaf(h, w0[i], a0); a1 = fmaf(h, w1[i], a1);
      a2 = fmaf(h, w2[i], a2); a3 = fmaf(h, w3[i], a3);
    }
    h1s[n * HP + ch] = fmaxf(a0, 0.f);
    h1s[n * HP + ch + 1] = fmaxf(a1, 0.f);
    h1s[n * HP + ch + 2] = fmaxf(a2, 0.f);
    h1s[n * HP + ch + 3] = fmaxf(a3, 0.f);
  }
  __syncthreads();
  float h1r[64];
#pragma unroll
  for (int i = 0; i < 64; ++i) h1r[i] = h1s[n * HP + i];
#pragma unroll
  for (int g = 0; g < 4; ++g) {
    const int ch = cb1 + g * 4;
    float a0 = b2[ch], a1 = b2[ch + 1], a2 = b2[ch + 2], a3 = b2[ch + 3];
    const float* w0 = w2t + ch * 64;
    const float* w1 = w0 + 64;
    const float* w2 = w1 + 64;
    const float* w3 = w2 + 64;
#pragma unroll
    for (int i = 0; i < 64; ++i) {
      const float h = h1r[i];
      a0 = fmaf(h, w0[i], a0); a1 = fmaf(h, w1[i], a1);
      a2 = fmaf(h, w2[i], a2); a3 = fmaf(h, w3[i], a3);
    }
    h2s[n * HP + ch] = fmaxf(a0, 0.f);
    h2s[n * HP + ch + 1] = fmaxf(a1, 0.f);
    h2s[n * HP + ch + 2] = fmaxf(a2, 0.f);
    h2s[n * HP + ch + 3] = fmaxf(a3, 0.f);
  }
  __syncthreads();
  float h2r[64];
#pragma unroll
  for (int i = 0; i < 64; ++i) h2r[i] = h2s[n * HP + i];
  __syncthreads();  // all h2 reads done before h3 overwrites arena
  const bool valid = n < c;
  const int cb3 = w * 32;
#pragma unroll
  for (int g = 0; g < 8; ++g) {
    const int ch = cb3 + g * 4;
    float a0 = b3[ch], a1 = b3[ch + 1], a2 = b3[ch + 2], a3 = b3[ch + 3];
    const float* w0 = w3t + ch * 64;
    const float* w1 = w0 + 64;
    const float* w2 = w1 + 64;
    const float* w3 = w2 + 64;
#pragma unroll
    for (int i = 0; i < 64; ++i) {
      const float h = h2r[i];
      a0 = fmaf(h, w0[i], a0); a1 = fmaf(h, w1[i], a1);
      a2 = fmaf(h, w2[i], a2); a3 = fmaf(h, w3[i], a3);
    }
    h3s[(ch) * HP + n] = valid ? fmaxf(a0, 0.f) : NEGINF;
    h3s[(ch + 1) * HP + n] = valid ? fmaxf(a1, 0.f) : NEGINF;
    h3s[(ch + 2) * HP + n] = valid ? fmaxf(a2, 0.f) : NEGINF;
    h3s[(ch + 3) * HP + n] = valid ? fmaxf(a3, 0.f) : NEGINF;
  }
  __syncthreads();
  if (tid < 128) {
    float m0 = NEGINF;
#pragma unroll
    for (int i = 0; i < 64; ++i) m0 = fmaxf(m0, h3s[tid * HP + i]);
    out[(size_t)pm * NOUT + tid] = (c == 0) ? 0.f : m0;
  }
}

extern "C" void kernel_launch(void* const* d_in, const int* in_sizes, int n_in,
                              void* d_out, int out_size, void* d_ws, size_t ws_size,
                              hipStream_t stream) {
  const float* x   = (const float*)d_in[0];
  const float* pos = (const float*)d_in[1];
  const float* W1 = (const float*)d_in[3];
  const float* b1 = (const float*)d_in[4];
  const float* W2 = (const float*)d_in[5];
  const float* b2 = (const float*)d_in[6];
  const float* W3 = (const float*)d_in[7];
  const float* b3 = (const float*)d_in[8];

  float* out          = (float*)d_out;
  float* out_selpos   = out + (size_t)NB * NM * NOUT;
  float* out_selbatch = out_selpos + (size_t)NB * NM * 3;

  float* ws_f = (float*)d_ws;
  float* selpos = ws_f + 540672;
  float* w1t    = ws_f + 565248;
  float* w2t    = ws_f + 569536;
  float* w3t    = ws_f + 573632;

  hipLaunchKernelGGL(prep_weights, dim3(34), dim3(256), 0, stream, W1, W2, W3, w1t, w2t, w3t);
  hipLaunchKernelGGL(fps_kernel, dim3(NB), dim3(FPS_T), 0, stream, pos, selpos, out_selpos, out_selbatch);
  hipLaunchKernelGGL(ballmlp_kernel, dim3(NB * NM), dim3(256), 0, stream,
                     x, pos, selpos, w1t, w2t, w3t, b1, b2, b3, out);
}